// Round 1
// baseline (210.809 us; speedup 1.0000x reference)
//
#include <hip/hip_runtime.h>
#include <math.h>

// SimpleSplitFF: sparse expert-choice MoE.
// x:(4,4096,1024) f32, controller:(1024,32), f1:(1024,32,128), bias:(32,128), f2:(32,128,1024)
// T=4 slots, g = s/4 groups. perm is one-hot over g per (b,t,e) scaled by softmax-over-g prob.
// Output is zero except <=512 token rows.

#define DM   1024
#define NE   32
#define FE   128
#define T4   4
#define NB   4
#define SS   4096
#define NGRP 1024
#define NROW 512                       // NB*T4*NE route rows
#define LP_STRIDE (NROW * NGRP)        // one K-split partial: 512*1024 floats

// ---------------------------------------------------------------------------
// K1: partial logits  Lp[ks][(b*4+t)*32+e][g] = sum_{d in ks-slice} x[b,4g+t,d]*ctrl[d,e]
//     + fused zeroing of d_out (each block zeroes its 32-token-row slice).
// grid (128, 4): x = 128-token tile, y = K-split (256 d each). block 256.
// ---------------------------------------------------------------------------
__global__ __launch_bounds__(256, 2)
void k_logits(const float* __restrict__ x, const float* __restrict__ ctrl,
              float* __restrict__ Lp, float* __restrict__ out)
{
    const int m      = blockIdx.x;
    const int ks     = blockIdx.y;
    const int tid    = threadIdx.x;
    const int base_s = m * 128;                 // 128 tokens, never straddles b (128|4096)
    const int b      = base_s >> 12;
    const int g0     = (base_s & 4095) >> 2;

    __shared__ float xT[64 * 132];   // [d][tok], stride 132: f4-aligned, <=2-way/4-even banks
    __shared__ float cs[64 * 32];    // [d][e]

    const int tokg = tid & 31;       // token quad (one full group: t=0..3)
    const int eg   = tid >> 5;       // 0..7 -> experts eg*4..+3

    float acc[4][4];
#pragma unroll
    for (int i = 0; i < 4; ++i)
#pragma unroll
        for (int j = 0; j < 4; ++j) acc[i][j] = 0.f;

    const int row0 = tid >> 2;       // 0..63 (staging map: 2-way LDS write aliasing only)
    const int f4i  = tid & 3;        // 0..3

    for (int kit = 0; kit < 4; ++kit) {
        const int k0 = ks * 256 + kit * 64;
        __syncthreads();
        // stage x tile transposed: 128 tok x 64 d
#pragma unroll
        for (int rr = 0; rr < 2; ++rr) {
            const int row = row0 + rr * 64;
            const float* xp = x + (size_t)(base_s + row) * DM + k0;
#pragma unroll
            for (int cr = 0; cr < 4; ++cr) {
                const int col = f4i + cr * 4;                 // f4-column 0..15
                const float4 v = *(const float4*)(xp + col * 4);
                const int d = col * 4;
                xT[(d + 0) * 132 + row] = v.x;
                xT[(d + 1) * 132 + row] = v.y;
                xT[(d + 2) * 132 + row] = v.z;
                xT[(d + 3) * 132 + row] = v.w;
            }
        }
        // stage controller chunk: 64 x 32 floats (natural layout)
        {
            const float4* cg = (const float4*)(ctrl + (size_t)k0 * NE);
            float4* cl = (float4*)cs;
            cl[tid]       = cg[tid];
            cl[tid + 256] = cg[tid + 256];
        }
        __syncthreads();
#pragma unroll 8
        for (int d = 0; d < 64; ++d) {
            const float4 xv = *(const float4*)(xT + d * 132 + tokg * 4);
            const float4 cv = *(const float4*)(cs + d * 32 + eg * 4);
            const float xa[4] = { xv.x, xv.y, xv.z, xv.w };
            const float ca[4] = { cv.x, cv.y, cv.z, cv.w };
#pragma unroll
            for (int i = 0; i < 4; ++i)
#pragma unroll
                for (int j = 0; j < 4; ++j) acc[i][j] += xa[i] * ca[j];
        }
    }

    // write partial logits: thread's 4 tokens are (g0+tokg, t=0..3)
    {
        float* Lb = Lp + (size_t)ks * LP_STRIDE;
        const int g = g0 + tokg;
#pragma unroll
        for (int i = 0; i < 4; ++i)
#pragma unroll
            for (int j = 0; j < 4; ++j) {
                const int row = (b * T4 + i) * NE + eg * 4 + j;
                Lb[(size_t)row * NGRP + g] = acc[i][j];
            }
    }

    // fused zero of this block's out slice: rows [base_s + ks*32, +32)
    {
        const float4 z = make_float4(0.f, 0.f, 0.f, 0.f);
        float4* o4 = (float4*)(out + (size_t)(base_s + ks * 32) * DM);
#pragma unroll 4
        for (int i = tid; i < 32 * DM / 4; i += 256) o4[i] = z;
    }
}

// ---------------------------------------------------------------------------
// K2: per-(b,e) block: route (argmax+softmax over g, per slot t), expert FFN,
//     atomic scatter into out. grid 128 = b*32+e, block 256 (4 waves).
// ---------------------------------------------------------------------------
__global__ __launch_bounds__(256, 1)
void k_expert(const float* __restrict__ x, const float* __restrict__ f1,
              const float* __restrict__ bias, const float* __restrict__ f2,
              const float* __restrict__ Lp, float* __restrict__ out)
{
    const int blk  = blockIdx.x;
    const int b    = blk >> 5;
    const int e    = blk & 31;
    const int tid  = threadIdx.x;
    const int lane = tid & 63;
    const int w    = tid >> 6;      // wave id = slot t for routing/staging

    __shared__ float xr[T4][DM];    // 4 selected token rows
    __shared__ float wl[64 * FE];   // f1 d-chunk
    __shared__ float vv[T4][FE];
    __shared__ float hh[T4][FE];
    __shared__ int   gS[T4];
    __shared__ float pS[T4];

    // --- route for slot t = w: online softmax + argmax over g (sum 4 K-partials) ---
    {
        const int r = (b * T4 + w) * NE + e;
        const float* L0 = Lp + (size_t)r * NGRP;
        float mx = -INFINITY, s = 0.f;
        int gm = 0;
#pragma unroll
        for (int c = 0; c < 4; ++c) {
            const int g0c = c * 256 + lane * 4;
            const float4 v0 = *(const float4*)(L0 + g0c);
            const float4 v1 = *(const float4*)(L0 + 1 * LP_STRIDE + g0c);
            const float4 v2 = *(const float4*)(L0 + 2 * LP_STRIDE + g0c);
            const float4 v3 = *(const float4*)(L0 + 3 * LP_STRIDE + g0c);
            const float l[4] = { v0.x + v1.x + v2.x + v3.x,
                                 v0.y + v1.y + v2.y + v3.y,
                                 v0.z + v1.z + v2.z + v3.z,
                                 v0.w + v1.w + v2.w + v3.w };
#pragma unroll
            for (int j = 0; j < 4; ++j) {
                const float lv = l[j];
                if (lv > mx) { s = s * __expf(mx - lv) + 1.f; mx = lv; gm = g0c + j; }
                else         { s += __expf(lv - mx); }
            }
        }
#pragma unroll
        for (int off = 1; off < 64; off <<= 1) {
            const float m2 = __shfl_xor(mx, off);
            const float s2 = __shfl_xor(s, off);
            const int   g2 = __shfl_xor(gm, off);
            const float mn = fmaxf(mx, m2);
            s  = s * __expf(mx - mn) + s2 * __expf(m2 - mn);
            gm = (m2 > mx) ? g2 : ((m2 == mx && g2 < gm) ? g2 : gm);
            mx = mn;
        }
        if (lane == 0) { gS[w] = gm; pS[w] = 1.f / s; }
    }
    __syncthreads();

    int   gl[T4];
    float pl[T4];
#pragma unroll
    for (int t = 0; t < T4; ++t) { gl[t] = gS[t]; pl[t] = pS[t]; }

    // --- stage the 4 selected token rows (wave w -> slot w) ---
    {
        const float4* src = (const float4*)(x + ((size_t)b * SS + gl[w] * 4 + w) * DM);
        float4* dst = (float4*)xr[w];
        for (int i = lane; i < DM / 4; i += 64) dst[i] = src[i];
    }
    __syncthreads();

    // --- v_t[f] = sum_d xr[t][d] * f1[d,e,f]; thread handles (f, 2 slots) ---
    {
        const int f    = tid & 127;
        const int half = tid >> 7;
        const float* x0 = xr[half * 2];
        const float* x1 = xr[half * 2 + 1];
        float a0 = 0.f, a1 = 0.f;
        for (int dc = 0; dc < 16; ++dc) {
            __syncthreads();
            {   // stage f1 chunk: 64 d-rows x 128 f (coalesced, natural layout)
                const int rr = tid >> 5, fq = tid & 31;
#pragma unroll
                for (int q = 0; q < 8; ++q) {
                    const int row = rr + q * 8;
                    const float4 v = *(const float4*)(f1 + (size_t)(dc * 64 + row) * (NE * FE)
                                                         + e * FE + fq * 4);
                    *(float4*)(wl + row * FE + fq * 4) = v;
                }
            }
            __syncthreads();
#pragma unroll 8
            for (int dl = 0; dl < 64; ++dl) {
                const float wv = wl[dl * FE + f];
                const int d = dc * 64 + dl;
                a0 += x0[d] * wv;
                a1 += x1[d] * wv;
            }
        }
        vv[half * 2][f]     = a0;
        vv[half * 2 + 1][f] = a1;
    }
    __syncthreads();

    // --- group slots by selected g (relu couples them), h_t = relu(bias + sum) ---
    if (tid < 128) {
        const int f = tid;
        const float bv = bias[e * FE + f];
#pragma unroll
        for (int t = 0; t < T4; ++t) {
            float u = bv;
#pragma unroll
            for (int t2 = 0; t2 < T4; ++t2)
                if (gl[t2] == gl[t]) u += pl[t2] * vv[t2][f];
            hh[t][f] = fmaxf(u, 0.f);
        }
    }
    __syncthreads();

    // --- y_t[d] = sum_f h_t[f] * f2[e,f,d]; scatter p_t*y_t into out ---
    {
        const int d0 = tid * 4;
        float a[T4][4];
#pragma unroll
        for (int t = 0; t < T4; ++t)
#pragma unroll
            for (int j = 0; j < 4; ++j) a[t][j] = 0.f;

        const float* f2b = f2 + (size_t)e * FE * DM + d0;
#pragma unroll 4
        for (int f = 0; f < FE; ++f) {
            const float4 w4 = *(const float4*)(f2b + (size_t)f * DM);
#pragma unroll
            for (int t = 0; t < T4; ++t) {
                const float hv = hh[t][f];
                a[t][0] += hv * w4.x; a[t][1] += hv * w4.y;
                a[t][2] += hv * w4.z; a[t][3] += hv * w4.w;
            }
        }
#pragma unroll
        for (int t = 0; t < T4; ++t) {
            const float p = pl[t];
            float* orow = out + ((size_t)b * SS + gl[t] * 4 + t) * DM + d0;
            atomicAdd(orow + 0, p * a[t][0]);
            atomicAdd(orow + 1, p * a[t][1]);
            atomicAdd(orow + 2, p * a[t][2]);
            atomicAdd(orow + 3, p * a[t][3]);
        }
    }
}

// ---------------------------------------------------------------------------
extern "C" void kernel_launch(void* const* d_in, const int* in_sizes, int n_in,
                              void* d_out, int out_size, void* d_ws, size_t ws_size,
                              hipStream_t stream)
{
    const float* x    = (const float*)d_in[0];
    const float* ctrl = (const float*)d_in[1];
    const float* f1   = (const float*)d_in[2];
    const float* bias = (const float*)d_in[3];
    const float* f2   = (const float*)d_in[4];
    float* out = (float*)d_out;
    float* Lp  = (float*)d_ws;          // 4 * 512 * 1024 floats = 8 MiB

    k_logits<<<dim3(128, 4), 256, 0, stream>>>(x, ctrl, Lp, out);
    k_expert<<<dim3(128), 256, 0, stream>>>(x, f1, bias, f2, Lp, out);
}

// Round 2
// 199.857 us; speedup vs baseline: 1.0548x; 1.0548x over previous
//
#include <hip/hip_runtime.h>
#include <math.h>

// SimpleSplitFF: sparse expert-choice MoE.
// x:(4,4096,1024) f32, controller:(1024,32), f1:(1024,32,128), bias:(32,128), f2:(32,128,1024)
// perm is one-hot over g per (b,t,e) scaled by softmax-over-g prob -> only 512 routed rows.

#define DM   1024
#define NE   32
#define FE   128
#define T4   4
#define SS   4096
#define NGRP 1024
#define NROW 512                       // NB*T4*NE route rows
#define LP_STRIDE (NROW * NGRP)        // one K-split partial: 512*1024 floats (2 MiB)
#define VP_OFF   524288                // float offset of Vp partials (aliases Lp splits 1-2)

// ---------------------------------------------------------------------------
// K1: partial logits Lp[ks][row][g] + fused zeroing of d_out. (unchanged)
// grid (128,4), block 256.
// ---------------------------------------------------------------------------
__global__ __launch_bounds__(256, 2)
void k_logits(const float* __restrict__ x, const float* __restrict__ ctrl,
              float* __restrict__ Lp, float* __restrict__ out)
{
    const int m      = blockIdx.x;
    const int ks     = blockIdx.y;
    const int tid    = threadIdx.x;
    const int base_s = m * 128;
    const int b      = base_s >> 12;
    const int g0     = (base_s & 4095) >> 2;

    __shared__ float xT[64 * 132];
    __shared__ float cs[64 * 32];

    const int tokg = tid & 31;
    const int eg   = tid >> 5;

    float acc[4][4];
#pragma unroll
    for (int i = 0; i < 4; ++i)
#pragma unroll
        for (int j = 0; j < 4; ++j) acc[i][j] = 0.f;

    const int row0 = tid >> 2;
    const int f4i  = tid & 3;

    for (int kit = 0; kit < 4; ++kit) {
        const int k0 = ks * 256 + kit * 64;
        __syncthreads();
#pragma unroll
        for (int rr = 0; rr < 2; ++rr) {
            const int row = row0 + rr * 64;
            const float* xp = x + (size_t)(base_s + row) * DM + k0;
#pragma unroll
            for (int cr = 0; cr < 4; ++cr) {
                const int col = f4i + cr * 4;
                const float4 v = *(const float4*)(xp + col * 4);
                const int d = col * 4;
                xT[(d + 0) * 132 + row] = v.x;
                xT[(d + 1) * 132 + row] = v.y;
                xT[(d + 2) * 132 + row] = v.z;
                xT[(d + 3) * 132 + row] = v.w;
            }
        }
        {
            const float4* cg = (const float4*)(ctrl + (size_t)k0 * NE);
            float4* cl = (float4*)cs;
            cl[tid]       = cg[tid];
            cl[tid + 256] = cg[tid + 256];
        }
        __syncthreads();
#pragma unroll 8
        for (int d = 0; d < 64; ++d) {
            const float4 xv = *(const float4*)(xT + d * 132 + tokg * 4);
            const float4 cv = *(const float4*)(cs + d * 32 + eg * 4);
            const float xa[4] = { xv.x, xv.y, xv.z, xv.w };
            const float ca[4] = { cv.x, cv.y, cv.z, cv.w };
#pragma unroll
            for (int i = 0; i < 4; ++i)
#pragma unroll
                for (int j = 0; j < 4; ++j) acc[i][j] += xa[i] * ca[j];
        }
    }

    {
        float* Lb = Lp + (size_t)ks * LP_STRIDE;
        const int g = g0 + tokg;
#pragma unroll
        for (int i = 0; i < 4; ++i)
#pragma unroll
            for (int j = 0; j < 4; ++j) {
                const int row = (b * T4 + i) * NE + eg * 4 + j;
                Lb[(size_t)row * NGRP + g] = acc[i][j];
            }
    }

    {
        const float4 z = make_float4(0.f, 0.f, 0.f, 0.f);
        float4* o4 = (float4*)(out + (size_t)(base_s + ks * 32) * DM);
#pragma unroll 4
        for (int i = tid; i < 32 * DM / 4; i += 256) o4[i] = z;
    }
}

// ---------------------------------------------------------------------------
// K2: route. grid 256, block 128 (2 waves, wave per row). Sums 4 K-partials,
// online softmax + argmax over g. Stores g (int bits) at Lp[row][0], p at
// Lp[row][1] — each wave overwrites only split-0 data it already read.
// ---------------------------------------------------------------------------
__global__ __launch_bounds__(128)
void k_route(float* __restrict__ Lp)
{
    const int r    = blockIdx.x * 2 + (threadIdx.x >> 6);
    const int lane = threadIdx.x & 63;
    const float* L0 = Lp + (size_t)r * NGRP;

    float mx = -INFINITY, s = 0.f;
    int gm = 0;
#pragma unroll
    for (int c = 0; c < 4; ++c) {
        const int g0c = c * 256 + lane * 4;
        const float4 v0 = *(const float4*)(L0 + g0c);
        const float4 v1 = *(const float4*)(L0 + 1 * LP_STRIDE + g0c);
        const float4 v2 = *(const float4*)(L0 + 2 * LP_STRIDE + g0c);
        const float4 v3 = *(const float4*)(L0 + 3 * LP_STRIDE + g0c);
        const float l[4] = { v0.x + v1.x + v2.x + v3.x,
                             v0.y + v1.y + v2.y + v3.y,
                             v0.z + v1.z + v2.z + v3.z,
                             v0.w + v1.w + v2.w + v3.w };
#pragma unroll
        for (int j = 0; j < 4; ++j) {
            const float lv = l[j];
            if (lv > mx) { s = s * __expf(mx - lv) + 1.f; mx = lv; gm = g0c + j; }
            else         { s += __expf(lv - mx); }
        }
    }
#pragma unroll
    for (int off = 1; off < 64; off <<= 1) {
        const float m2 = __shfl_xor(mx, off);
        const float s2 = __shfl_xor(s, off);
        const int   g2 = __shfl_xor(gm, off);
        const float mn = fmaxf(mx, m2);
        s  = s * __expf(mx - mn) + s2 * __expf(m2 - mn);
        gm = (m2 > mx) ? g2 : ((m2 == mx && g2 < gm) ? g2 : gm);
        mx = mn;
    }
    if (lane == 0) {
        ((int*)Lp)[(size_t)r * NGRP] = gm;
        Lp[(size_t)r * NGRP + 1] = 1.f / s;
    }
}

// ---------------------------------------------------------------------------
// K3: up-projection partials. grid 512 = (dc 16)<<5 | (e 32), block 256.
// Vp[dc][e][row16][128] = sum over 64-d chunk of x_sel * f1[:,e,:].
// f1 read direct from global (within-wave broadcast -> L1-friendly).
// ---------------------------------------------------------------------------
__global__ __launch_bounds__(256, 2)
void k_up(const float* __restrict__ x, const float* __restrict__ f1,
          float* __restrict__ ws)
{
    const int e   = blockIdx.x & 31;
    const int dc  = blockIdx.x >> 5;       // 0..15 -> d chunk of 64
    const int tid = threadIdx.x;

    __shared__ float xs[16 * 68];          // 16 rows x 64 d, pad 68 (bank-clean)
    __shared__ int   gS[16];

    if (tid < 16) {
        const int b = tid >> 2, t = tid & 3;
        const int r = (b * T4 + t) * NE + e;
        gS[tid] = ((const int*)ws)[(size_t)r * NGRP];
    }
    __syncthreads();

    {   // stage x slices: one float4 per thread (row = tid>>4, f4col = tid&15)
        const int row = tid >> 4;
        const int f4c = tid & 15;
        const int b = row >> 2, t = row & 3;
        const int s = b * SS + gS[row] * 4 + t;
        const float4 v = *(const float4*)(x + (size_t)s * DM + dc * 64 + f4c * 4);
        xs[row * 68 + f4c * 4 + 0] = v.x;
        xs[row * 68 + f4c * 4 + 1] = v.y;
        xs[row * 68 + f4c * 4 + 2] = v.z;
        xs[row * 68 + f4c * 4 + 3] = v.w;
    }
    __syncthreads();

    const int f4 = tid & 31;               // 4 f's
    const int rw = tid >> 5;               // 0..7 -> rows rw*2, rw*2+1
    const float* f1p = f1 + (size_t)(dc * 64) * (NE * FE) + e * FE + f4 * 4;
    const float* x0 = xs + (rw * 2) * 68;
    const float* x1 = xs + (rw * 2 + 1) * 68;

    float a0[4] = {0.f, 0.f, 0.f, 0.f}, a1[4] = {0.f, 0.f, 0.f, 0.f};
#pragma unroll 8
    for (int dl = 0; dl < 64; ++dl) {
        const float4 w4 = *(const float4*)(f1p + (size_t)dl * (NE * FE));
        const float xa = x0[dl], xb = x1[dl];
        a0[0] += xa * w4.x; a0[1] += xa * w4.y; a0[2] += xa * w4.z; a0[3] += xa * w4.w;
        a1[0] += xb * w4.x; a1[1] += xb * w4.y; a1[2] += xb * w4.z; a1[3] += xb * w4.w;
    }

    float* Vp = ws + VP_OFF + (size_t)(dc * 32 + e) * (16 * FE);
    *(float4*)(Vp + (rw * 2)     * FE + f4 * 4) = make_float4(a0[0], a0[1], a0[2], a0[3]);
    *(float4*)(Vp + (rw * 2 + 1) * FE + f4 * 4) = make_float4(a1[0], a1[1], a1[2], a1[3]);
}

// ---------------------------------------------------------------------------
// K4: reduce partials, group-coupled relu, down-projection, atomic scatter.
// grid 256 = (dt 8)<<5 | (e 32), block 256. f2 read direct from global.
// ---------------------------------------------------------------------------
__global__ __launch_bounds__(256, 2)
void k_down(const float* __restrict__ f2, const float* __restrict__ bias,
            const float* __restrict__ ws, float* __restrict__ out)
{
    const int e   = blockIdx.x & 31;
    const int dt  = blockIdx.x >> 5;       // 0..7 -> 128-d output tile
    const int tid = threadIdx.x;

    __shared__ float vv[16 * 132];
    __shared__ float hh[16 * 132];
    __shared__ int   gS[16];
    __shared__ float pS[16];

    if (tid < 16) {
        const int b = tid >> 2, t = tid & 3;
        const int r = (b * T4 + t) * NE + e;
        gS[tid] = ((const int*)ws)[(size_t)r * NGRP];
        pS[tid] = ws[(size_t)r * NGRP + 1];
    }

    {   // reduce the 16 K-chunk partials: 2048 outputs, 8 per thread
        const float* Vp = ws + VP_OFF;
#pragma unroll
        for (int q = 0; q < 8; ++q) {
            const int i = tid + q * 256;   // i = row*128 + f
            float s = 0.f;
#pragma unroll
            for (int dc = 0; dc < 16; ++dc)
                s += Vp[(size_t)(dc * 32 + e) * (16 * FE) + i];
            vv[(i >> 7) * 132 + (i & 127)] = s;
        }
    }
    __syncthreads();

    // h_t = relu(bias + sum over slots with same selected g)
    if (tid < 128) {
        const int f = tid;
        const float bv = bias[e * FE + f];
#pragma unroll
        for (int b = 0; b < 4; ++b) {
            int   g[T4]; float p[T4], vl[T4];
#pragma unroll
            for (int t = 0; t < T4; ++t) {
                g[t] = gS[b * 4 + t]; p[t] = pS[b * 4 + t];
                vl[t] = vv[(b * 4 + t) * 132 + f];
            }
#pragma unroll
            for (int t = 0; t < T4; ++t) {
                float u = bv;
#pragma unroll
                for (int t2 = 0; t2 < T4; ++t2)
                    if (g[t2] == g[t]) u += p[t2] * vl[t2];
                hh[(b * 4 + t) * 132 + f] = fmaxf(u, 0.f);
            }
        }
    }
    __syncthreads();

    const int d4 = tid & 31;               // 4 d's
    const int rw = tid >> 5;               // rows rw*2, rw*2+1
    const float* f2p = f2 + (size_t)e * FE * DM + dt * 128 + d4 * 4;
    const float* h0 = hh + (rw * 2) * 132;
    const float* h1 = hh + (rw * 2 + 1) * 132;

    float a0[4] = {0.f, 0.f, 0.f, 0.f}, a1[4] = {0.f, 0.f, 0.f, 0.f};
#pragma unroll 8
    for (int f = 0; f < FE; ++f) {
        const float4 w4 = *(const float4*)(f2p + (size_t)f * DM);
        const float ha = h0[f], hb = h1[f];
        a0[0] += ha * w4.x; a0[1] += ha * w4.y; a0[2] += ha * w4.z; a0[3] += ha * w4.w;
        a1[0] += hb * w4.x; a1[1] += hb * w4.y; a1[2] += hb * w4.z; a1[3] += hb * w4.w;
    }

#pragma unroll
    for (int h = 0; h < 2; ++h) {
        const int row = rw * 2 + h;
        const int b = row >> 2, t = row & 3;
        const float p = pS[row];
        const float* a = h ? a1 : a0;
        float* orow = out + ((size_t)(b * SS + gS[row] * 4 + t)) * DM + dt * 128 + d4 * 4;
        atomicAdd(orow + 0, p * a[0]);
        atomicAdd(orow + 1, p * a[1]);
        atomicAdd(orow + 2, p * a[2]);
        atomicAdd(orow + 3, p * a[3]);
    }
}

// ---------------------------------------------------------------------------
extern "C" void kernel_launch(void* const* d_in, const int* in_sizes, int n_in,
                              void* d_out, int out_size, void* d_ws, size_t ws_size,
                              hipStream_t stream)
{
    const float* x    = (const float*)d_in[0];
    const float* ctrl = (const float*)d_in[1];
    const float* f1   = (const float*)d_in[2];
    const float* bias = (const float*)d_in[3];
    const float* f2   = (const float*)d_in[4];
    float* out = (float*)d_out;
    float* ws  = (float*)d_ws;             // 8 MiB total (Lp; Vp aliases splits 1-2)

    k_logits<<<dim3(128, 4), 256, 0, stream>>>(x, ctrl, ws, out);
    k_route <<<dim3(256),    128, 0, stream>>>(ws);
    k_up    <<<dim3(512),    256, 0, stream>>>(x, f1, ws);
    k_down  <<<dim3(256),    256, 0, stream>>>(f2, bias, ws, out);
}

// Round 3
// 193.113 us; speedup vs baseline: 1.0916x; 1.0349x over previous
//
#include <hip/hip_runtime.h>
#include <math.h>

// SimpleSplitFF: sparse expert-choice MoE.
// x:(4,4096,1024) f32, controller:(1024,32), f1:(1024,32,128), bias:(32,128), f2:(32,128,1024)
// perm is one-hot over g per (b,t,e) scaled by softmax-over-g prob -> only 512 routed rows.

#define DM   1024
#define NE   32
#define FE   128
#define T4   4
#define SS   4096
#define NGRP 1024
#define NROW 512                       // route rows r = (b*4+t)*32+e = row16*32+e
#define LP_STRIDE (NROW * NGRP)        // one K-split partial (2 MiB)
#define VP_OFF   524288                // Vp partials: aliases Lp splits 1-2 (dead after route)
#define HH_OFF   1572864               // Hh: aliases Lp split 3 (dead after route)

// ---------------------------------------------------------------------------
// K1: partial logits Lp[ks][row][g] + fused zeroing of d_out.
// grid (256,4) = 1024 blocks (4/CU): 64-token tile, K-split 256.
// ---------------------------------------------------------------------------
__global__ __launch_bounds__(256, 4)
void k_logits(const float* __restrict__ x, const float* __restrict__ ctrl,
              float* __restrict__ Lp, float* __restrict__ out)
{
    const int m      = blockIdx.x;
    const int ks     = blockIdx.y;
    const int tid    = threadIdx.x;
    const int base_s = m * 64;                 // 64 tokens (16 groups), never straddles b
    const int b      = base_s >> 12;
    const int g0     = (base_s & 4095) >> 2;

    __shared__ float xT[64 * 68];   // [d][tok], pad 68 -> <=2-way aliasing
    __shared__ float cs[64 * 32];   // [d][e]

    const int tq = tid & 15;        // token quad (group), t=0..3
    const int eg = tid >> 4;        // 0..15 -> experts eg*2, eg*2+1

    float acc[4][2];
#pragma unroll
    for (int i = 0; i < 4; ++i) { acc[i][0] = 0.f; acc[i][1] = 0.f; }

    const int row0 = tid >> 2;      // 0..63 staging row (token)
    const int f4i  = tid & 3;

    for (int kit = 0; kit < 4; ++kit) {
        const int k0 = ks * 256 + kit * 64;
        __syncthreads();
        {   // stage x tile transposed: 64 tok x 64 d
            const float* xp = x + (size_t)(base_s + row0) * DM + k0;
#pragma unroll
            for (int cr = 0; cr < 4; ++cr) {
                const int col = f4i + cr * 4;                 // f4-column 0..15
                const float4 v = *(const float4*)(xp + col * 4);
                const int d = col * 4;
                xT[(d + 0) * 68 + row0] = v.x;
                xT[(d + 1) * 68 + row0] = v.y;
                xT[(d + 2) * 68 + row0] = v.z;
                xT[(d + 3) * 68 + row0] = v.w;
            }
        }
        {   // stage controller chunk 64 x 32
            const float4* cg = (const float4*)(ctrl + (size_t)k0 * NE);
            float4* cl = (float4*)cs;
            cl[tid]       = cg[tid];
            cl[tid + 256] = cg[tid + 256];
        }
        __syncthreads();
#pragma unroll 8
        for (int d = 0; d < 64; ++d) {
            const float4 xv = *(const float4*)(xT + d * 68 + tq * 4);
            const float2 cv = *(const float2*)(cs + d * 32 + eg * 2);
            const float xa[4] = { xv.x, xv.y, xv.z, xv.w };
#pragma unroll
            for (int i = 0; i < 4; ++i) {
                acc[i][0] += xa[i] * cv.x;
                acc[i][1] += xa[i] * cv.y;
            }
        }
    }

    {   // write partial logits
        float* Lb = Lp + (size_t)ks * LP_STRIDE;
        const int g = g0 + tq;
#pragma unroll
        for (int i = 0; i < 4; ++i)
#pragma unroll
            for (int j = 0; j < 2; ++j) {
                const int row = (b * T4 + i) * NE + eg * 2 + j;
                Lb[(size_t)row * NGRP + g] = acc[i][j];
            }
    }

    {   // fused zero: rows [base_s + ks*16, +16)
        const float4 z = make_float4(0.f, 0.f, 0.f, 0.f);
        float4* o4 = (float4*)(out + (size_t)(base_s + ks * 16) * DM);
#pragma unroll 4
        for (int i = tid; i < 16 * DM / 4; i += 256) o4[i] = z;
    }
}

// ---------------------------------------------------------------------------
// K2: route. grid 256 x 128 thr (wave per row). Sums 4 K-partials, online
// softmax+argmax over g. Stores g (int bits) at Lp[row][0], p at Lp[row][1].
// ---------------------------------------------------------------------------
__global__ __launch_bounds__(128)
void k_route(float* __restrict__ Lp)
{
    const int r    = blockIdx.x * 2 + (threadIdx.x >> 6);
    const int lane = threadIdx.x & 63;
    const float* L0 = Lp + (size_t)r * NGRP;

    float mx = -INFINITY, s = 0.f;
    int gm = 0;
#pragma unroll
    for (int c = 0; c < 4; ++c) {
        const int g0c = c * 256 + lane * 4;
        const float4 v0 = *(const float4*)(L0 + g0c);
        const float4 v1 = *(const float4*)(L0 + 1 * LP_STRIDE + g0c);
        const float4 v2 = *(const float4*)(L0 + 2 * LP_STRIDE + g0c);
        const float4 v3 = *(const float4*)(L0 + 3 * LP_STRIDE + g0c);
        const float l[4] = { v0.x + v1.x + v2.x + v3.x,
                             v0.y + v1.y + v2.y + v3.y,
                             v0.z + v1.z + v2.z + v3.z,
                             v0.w + v1.w + v2.w + v3.w };
#pragma unroll
        for (int j = 0; j < 4; ++j) {
            const float lv = l[j];
            if (lv > mx) { s = s * __expf(mx - lv) + 1.f; mx = lv; gm = g0c + j; }
            else         { s += __expf(lv - mx); }
        }
    }
#pragma unroll
    for (int off = 1; off < 64; off <<= 1) {
        const float m2 = __shfl_xor(mx, off);
        const float s2 = __shfl_xor(s, off);
        const int   g2 = __shfl_xor(gm, off);
        const float mn = fmaxf(mx, m2);
        s  = s * __expf(mx - mn) + s2 * __expf(m2 - mn);
        gm = (m2 > mx) ? g2 : ((m2 == mx && g2 < gm) ? g2 : gm);
        mx = mn;
    }
    if (lane == 0) {
        ((int*)Lp)[(size_t)r * NGRP] = gm;
        Lp[(size_t)r * NGRP + 1] = 1.f / s;
    }
}

// ---------------------------------------------------------------------------
// K3: up-projection partials. grid 1024 = (rh 2)<<9 | (dc 16)<<5 | (e 32).
// Block: 8 rows x 64-d chunk x expert e. 1 row/thread, unroll-16 f1 stream.
// ---------------------------------------------------------------------------
__global__ __launch_bounds__(256, 4)
void k_up(const float* __restrict__ x, const float* __restrict__ f1,
          float* __restrict__ ws)
{
    const int e   = blockIdx.x & 31;
    const int dc  = (blockIdx.x >> 5) & 15;    // 64-d chunk
    const int rh  = blockIdx.x >> 9;           // row half: rows rh*8..+7
    const int tid = threadIdx.x;

    __shared__ float xs[8 * 68];
    __shared__ int   gS[8];

    if (tid < 8) {
        const int r = (rh * 8 + tid) * NE + e; // row16*32+e
        gS[tid] = ((const int*)ws)[(size_t)r * NGRP];
    }
    __syncthreads();

    if (tid < 128) {   // stage 8 rows x 64 d
        const int row = tid >> 4;              // local row
        const int f4c = tid & 15;
        const int grow = rh * 8 + row;
        const int bq = grow >> 2, t = grow & 3;
        const int s = bq * SS + gS[row] * 4 + t;
        const float4 v = *(const float4*)(x + (size_t)s * DM + dc * 64 + f4c * 4);
        xs[row * 68 + f4c * 4 + 0] = v.x;
        xs[row * 68 + f4c * 4 + 1] = v.y;
        xs[row * 68 + f4c * 4 + 2] = v.z;
        xs[row * 68 + f4c * 4 + 3] = v.w;
    }
    __syncthreads();

    const int f4 = tid & 31;                   // 4 f's
    const int rw = tid >> 5;                   // local row 0..7
    const float* f1p = f1 + (size_t)(dc * 64) * (NE * FE) + e * FE + f4 * 4;
    const float* xp  = xs + rw * 68;

    float a[4] = {0.f, 0.f, 0.f, 0.f};
#pragma unroll 16
    for (int dl = 0; dl < 64; ++dl) {
        const float4 w4 = *(const float4*)(f1p + (size_t)dl * (NE * FE));
        const float xa = xp[dl];
        a[0] += xa * w4.x; a[1] += xa * w4.y; a[2] += xa * w4.z; a[3] += xa * w4.w;
    }

    float* Vp = ws + VP_OFF + (size_t)(dc * 32 + e) * (16 * FE);
    *(float4*)(Vp + (rh * 8 + rw) * FE + f4 * 4) = make_float4(a[0], a[1], a[2], a[3]);
}

// ---------------------------------------------------------------------------
// K4: reduce 16 K-chunk partials once, group-coupled relu, fold p_t.
// grid 128 = (b 4)<<5 | (e 32). Hh[e][row16][f].
// ---------------------------------------------------------------------------
__global__ __launch_bounds__(256, 4)
void k_act(const float* __restrict__ bias, float* __restrict__ ws)
{
    const int e   = blockIdx.x & 31;
    const int b   = blockIdx.x >> 5;
    const int tid = threadIdx.x;

    __shared__ float vv[T4][FE];
    __shared__ int   gS[T4];
    __shared__ float pS[T4];

    if (tid < 4) {
        const int r = (b * T4 + tid) * NE + e;
        gS[tid] = ((const int*)ws)[(size_t)r * NGRP];
        pS[tid] = ws[(size_t)r * NGRP + 1];
    }

    const float* Vp = ws + VP_OFF;
#pragma unroll
    for (int q = 0; q < 2; ++q) {
        const int idx = tid + q * 256;         // t*128+f
        const int t = idx >> 7, f = idx & 127;
        float s = 0.f;
#pragma unroll
        for (int dc = 0; dc < 16; ++dc)
            s += Vp[(size_t)(dc * 32 + e) * (16 * FE) + (b * T4 + t) * FE + f];
        vv[t][f] = s;
    }
    __syncthreads();

#pragma unroll
    for (int q = 0; q < 2; ++q) {
        const int idx = tid + q * 256;
        const int t = idx >> 7, f = idx & 127;
        float u = bias[e * FE + f];
#pragma unroll
        for (int t2 = 0; t2 < T4; ++t2)
            if (gS[t2] == gS[t]) u += pS[t2] * vv[t2][f];
        ws[HH_OFF + (size_t)e * (16 * FE) + (b * T4 + t) * FE + f] =
            pS[t] * fmaxf(u, 0.f);             // p_t folded
    }
}

// ---------------------------------------------------------------------------
// K5: down-projection + atomic scatter. grid 512 = (rh 2)<<8 | (dt 8)<<5 | (e 32).
// Block: 8 rows x 128-d tile. Reads Hh (tiny) + streams f2 with unroll 16.
// ---------------------------------------------------------------------------
__global__ __launch_bounds__(256, 2)
void k_down(const float* __restrict__ f2, const float* __restrict__ ws,
            float* __restrict__ out)
{
    const int e   = blockIdx.x & 31;
    const int dt  = (blockIdx.x >> 5) & 7;     // 128-d output tile
    const int rh  = blockIdx.x >> 8;           // rows rh*8..+7
    const int tid = threadIdx.x;

    __shared__ float hs[8 * FE];
    __shared__ int   gS[8];

    if (tid < 8) {
        const int r = (rh * 8 + tid) * NE + e;
        gS[tid] = ((const int*)ws)[(size_t)r * NGRP];
    }
    {   // stage Hh rows: 8 x 128
        const int row = tid >> 5, f4 = tid & 31;
        const float4 v = *(const float4*)(ws + HH_OFF + (size_t)e * (16 * FE)
                                             + (rh * 8 + row) * FE + f4 * 4);
        *(float4*)(hs + row * FE + f4 * 4) = v;
    }
    __syncthreads();

    const int d4 = tid & 31;                   // 4 d's
    const int rw = tid >> 5;                   // local row 0..7
    const float* f2p = f2 + (size_t)e * FE * DM + dt * 128 + d4 * 4;
    const float* hp  = hs + rw * FE;

    float a[4] = {0.f, 0.f, 0.f, 0.f};
#pragma unroll 16
    for (int f = 0; f < FE; ++f) {
        const float4 w4 = *(const float4*)(f2p + (size_t)f * DM);
        const float ha = hp[f];
        a[0] += ha * w4.x; a[1] += ha * w4.y; a[2] += ha * w4.z; a[3] += ha * w4.w;
    }

    const int grow = rh * 8 + rw;
    const int bq = grow >> 2, t = grow & 3;
    float* orow = out + ((size_t)(bq * SS + gS[rw] * 4 + t)) * DM + dt * 128 + d4 * 4;
    atomicAdd(orow + 0, a[0]);
    atomicAdd(orow + 1, a[1]);
    atomicAdd(orow + 2, a[2]);
    atomicAdd(orow + 3, a[3]);
}

// ---------------------------------------------------------------------------
extern "C" void kernel_launch(void* const* d_in, const int* in_sizes, int n_in,
                              void* d_out, int out_size, void* d_ws, size_t ws_size,
                              hipStream_t stream)
{
    const float* x    = (const float*)d_in[0];
    const float* ctrl = (const float*)d_in[1];
    const float* f1   = (const float*)d_in[2];
    const float* bias = (const float*)d_in[3];
    const float* f2   = (const float*)d_in[4];
    float* out = (float*)d_out;
    float* ws  = (float*)d_ws;             // uses 8 MiB (Lp; Vp/Hh alias splits 1-3)

    k_logits<<<dim3(256, 4), 256, 0, stream>>>(x, ctrl, ws, out);
    k_route <<<dim3(256),    128, 0, stream>>>(ws);
    k_up    <<<dim3(1024),   256, 0, stream>>>(x, f1, ws);
    k_act   <<<dim3(128),    256, 0, stream>>>(bias, ws);
    k_down  <<<dim3(512),    256, 0, stream>>>(f2, ws, out);
}